// Round 3
// baseline (301.361 us; speedup 1.0000x reference)
//
#include <hip/hip_runtime.h>
#include <math.h>

#define N_OBJ 1024
#define C_DET 8
#define C_SEG 4
#define HW    784      // 28*28
#define HW4   196      // HW/4 (float4 units)
#define NBLK  98       // 98*256*8 == 200704 == N_OBJ*HW4 exactly
#define TOTB  (C_DET * NBLK)   // 784 blocks
#define NPART (TOTB * 5)       // 3920 partial floats

typedef float f32x4 __attribute__((ext_vector_type(4)));

// d_ws layout: float partial[NPART]; unsigned counter at word NPART.
// partial[(c*NBLK+bx)*5 + k]: k=0 denom partial, k=1..4 A[c][k-1] partial.

__global__ __launch_bounds__(256) void fused_kernel(
    const float* __restrict__ det,        // [N_OBJ, C_DET, HW]
    const float* __restrict__ seg,        // [N_OBJ, C_DET, C_SEG, HW]
    const float* __restrict__ det_class,  // [N_OBJ, C_DET]
    const int* __restrict__ edge_i,
    const int* __restrict__ edge_j,
    const int n_edges,
    float* __restrict__ partial,
    unsigned* __restrict__ counter,
    float* __restrict__ out)
{
    const int c   = blockIdx.y;
    const int bx  = blockIdx.x;
    const int tid = threadIdx.x;

    float accD = 0.f, a0 = 0.f, a1 = 0.f, a2 = 0.f, a3 = 0.f;

    const int base = bx * 256 + tid;   // 0..25087
    const int step = NBLK * 256;       // 25088

    auto body = [&](int t4) {
        const int n  = t4 / HW4;                 // magic-mul div
        const int p4 = t4 - n * HW4;
        const int drow = (n * C_DET + c) * HW + p4 * 4;
        const f32x4 d = __builtin_nontemporal_load(
            reinterpret_cast<const f32x4*>(det + drow));
        const int srow = (n * C_DET + c) * (C_SEG * HW) + p4 * 4;
        const f32x4 s0 = __builtin_nontemporal_load(
            reinterpret_cast<const f32x4*>(seg + srow + 0 * HW));
        const f32x4 s1 = __builtin_nontemporal_load(
            reinterpret_cast<const f32x4*>(seg + srow + 1 * HW));
        const f32x4 s2 = __builtin_nontemporal_load(
            reinterpret_cast<const f32x4*>(seg + srow + 2 * HW));
        const f32x4 s3 = __builtin_nontemporal_load(
            reinterpret_cast<const f32x4*>(seg + srow + 3 * HW));
        accD += (d.x + d.y) + (d.z + d.w);
        a0 += s0.x * d.x + s0.y * d.y + s0.z * d.z + s0.w * d.w;
        a1 += s1.x * d.x + s1.y * d.y + s1.z * d.z + s1.w * d.w;
        a2 += s2.x * d.x + s2.y * d.y + s2.z * d.z + s2.w * d.w;
        a3 += s3.x * d.x + s3.y * d.y + s3.z * d.z + s3.w * d.w;
    };

    #pragma unroll 2                    // 10 outstanding 16B loads/thread
    for (int it = 0; it < 8; ++it) body(base + it * step);

    // ---- block-reduce 5 scalars: wave shuffle -> LDS -> partial store ----
    __shared__ float sred[5][4];
    const int lane = tid & 63;
    const int wv   = tid >> 6;
    float vals[5] = {accD, a0, a1, a2, a3};
    #pragma unroll
    for (int k = 0; k < 5; ++k) {
        float v = vals[k];
        #pragma unroll
        for (int off = 32; off > 0; off >>= 1) v += __shfl_down(v, off, 64);
        if (lane == 0) sred[k][wv] = v;
    }
    __syncthreads();
    if (tid < 5) {
        partial[(c * NBLK + bx) * 5 + tid] =
            sred[tid][0] + sred[tid][1] + sred[tid][2] + sred[tid][3];
    }

    // ---- last-block-finishes handoff (device-scope, cross-XCD safe) ----
    __threadfence();                    // release: partial stores -> device scope
    __syncthreads();                    // all lanes fenced before the ticket bump
    __shared__ unsigned oldc;
    if (tid == 0) oldc = atomicAdd(counter, 1u);   // device-scope by default
    __syncthreads();
    if (oldc != TOTB - 1) return;

    // ================== finalize (last block only) ==================
    // Prefetch det_class into registers first to hide the cold HBM miss
    // behind the stage-1 partial reduction.
    f32x4 ra[4], rb[4];
    #pragma unroll
    for (int r = 0; r < 4; ++r) {
        const int n = tid + 256 * r;
        ra[r] = *reinterpret_cast<const f32x4*>(det_class + n * C_DET);
        rb[r] = *reinterpret_cast<const f32x4*>(det_class + n * C_DET + 4);
    }

    __threadfence();                    // acquire: see other blocks' partials

    // Stage 1: reduce 3920 partials -> DA[c*5+k] (k=0 denom, 1..4 A[c][s]).
    __shared__ float DA[C_DET * 5];
    if (tid < C_DET * 5) DA[tid] = 0.f;
    __syncthreads();
    for (int f = tid; f < NPART; f += 256) {
        const int cb = f / 5;
        const int k  = f - cb * 5;
        const int cc = cb / NBLK;
        atomicAdd(&DA[cc * 5 + k], partial[f]);
    }
    __syncthreads();

    // Stage 2: per-edge weights accumulated onto det class j.
    __shared__ float wsh[C_DET];
    if (tid < C_DET) wsh[tid] = 0.f;
    __syncthreads();
    if (tid < n_edges) {
        const int i = edge_i[tid];
        const int j = edge_j[tid];
        atomicAdd(&wsh[j], DA[j * 5 + 1 + i] / DA[j * 5]);
    }
    __syncthreads();

    float wl[C_DET];
    #pragma unroll
    for (int k = 0; k < C_DET; ++k) wl[k] = wsh[k];

    // Stage 3: probs = det_class @ w; loss = mean(-clip(log p, -100)).
    float acc = 0.f;
    #pragma unroll
    for (int r = 0; r < 4; ++r) {
        const float p = ra[r].x * wl[0] + ra[r].y * wl[1]
                      + ra[r].z * wl[2] + ra[r].w * wl[3]
                      + rb[r].x * wl[4] + rb[r].y * wl[5]
                      + rb[r].z * wl[6] + rb[r].w * wl[7];
        acc += -fmaxf(logf(p), -100.f);
    }

    __shared__ float fred[4];
    float v = acc;
    #pragma unroll
    for (int off = 32; off > 0; off >>= 1) v += __shfl_down(v, off, 64);
    if (lane == 0) fred[wv] = v;
    __syncthreads();
    if (tid == 0)
        out[0] = (fred[0] + fred[1] + fred[2] + fred[3]) * (1.0f / N_OBJ);
}

extern "C" void kernel_launch(void* const* d_in, const int* in_sizes, int n_in,
                              void* d_out, int out_size, void* d_ws, size_t ws_size,
                              hipStream_t stream) {
    const float* det_class = (const float*)d_in[0];   // [1024, 8]
    const float* det       = (const float*)d_in[1];   // [1024, 8, 28, 28]
    const float* seg       = (const float*)d_in[2];   // [1024, 8, 4, 28, 28]
    const int*   edge_i    = (const int*)d_in[3];
    const int*   edge_j    = (const int*)d_in[4];
    const int    n_edges   = in_sizes[3];
    float* out = (float*)d_out;
    float* partial = (float*)d_ws;
    unsigned* counter = (unsigned*)((char*)d_ws + NPART * sizeof(float));

    hipMemsetAsync(counter, 0, sizeof(unsigned), stream);   // graph-capturable
    fused_kernel<<<dim3(NBLK, C_DET), 256, 0, stream>>>(
        det, seg, det_class, edge_i, edge_j, n_edges, partial, counter, out);
}

// Round 4
// 180.948 us; speedup vs baseline: 1.6655x; 1.6655x over previous
//
#include <hip/hip_runtime.h>
#include <math.h>

#define N_OBJ 1024
#define C_DET 8
#define C_SEG 4
#define HW    784      // 28*28
#define HW4   196      // HW/4 (float4 units)
#define NBLK  196      // 196*256*4 == 200704 == N_OBJ*HW4 exactly
#define ITERS 4
#define NPART (C_DET * NBLK * 5)   // 7840 partial floats

typedef float f32x4 __attribute__((ext_vector_type(4)));

// d_ws layout: float partial[NPART].
// partial[(c*NBLK+bx)*5 + k]: k=0 denom partial, k=1..4 A[c][k-1] partial.

__global__ __launch_bounds__(256) void overlap_kernel(
    const float* __restrict__ det,   // [N_OBJ, C_DET, HW]
    const float* __restrict__ seg,   // [N_OBJ, C_DET, C_SEG, HW]
    float* __restrict__ partial)
{
    const int c   = blockIdx.y;
    const int bx  = blockIdx.x;
    const int tid = threadIdx.x;

    float accD = 0.f, a0 = 0.f, a1 = 0.f, a2 = 0.f, a3 = 0.f;

    const int base = bx * 256 + tid;   // 0..50175
    const int step = NBLK * 256;       // 50176

    auto body = [&](int t4) {
        const int n  = t4 / HW4;                 // magic-mul div
        const int p4 = t4 - n * HW4;
        const int drow = (n * C_DET + c) * HW + p4 * 4;
        const f32x4 d = __builtin_nontemporal_load(
            reinterpret_cast<const f32x4*>(det + drow));
        const int srow = (n * C_DET + c) * (C_SEG * HW) + p4 * 4;
        const f32x4 s0 = __builtin_nontemporal_load(
            reinterpret_cast<const f32x4*>(seg + srow + 0 * HW));
        const f32x4 s1 = __builtin_nontemporal_load(
            reinterpret_cast<const f32x4*>(seg + srow + 1 * HW));
        const f32x4 s2 = __builtin_nontemporal_load(
            reinterpret_cast<const f32x4*>(seg + srow + 2 * HW));
        const f32x4 s3 = __builtin_nontemporal_load(
            reinterpret_cast<const f32x4*>(seg + srow + 3 * HW));
        accD += (d.x + d.y) + (d.z + d.w);
        a0 += s0.x * d.x + s0.y * d.y + s0.z * d.z + s0.w * d.w;
        a1 += s1.x * d.x + s1.y * d.y + s1.z * d.z + s1.w * d.w;
        a2 += s2.x * d.x + s2.y * d.y + s2.z * d.z + s2.w * d.w;
        a3 += s3.x * d.x + s3.y * d.y + s3.z * d.z + s3.w * d.w;
    };

    #pragma unroll 2                    // 10 outstanding 16B loads/thread
    for (int it = 0; it < ITERS; ++it) body(base + it * step);

    // ---- block-reduce 5 scalars: wave shuffle -> LDS -> partial store ----
    __shared__ float sred[5][4];
    const int lane = tid & 63;
    const int wv   = tid >> 6;
    float vals[5] = {accD, a0, a1, a2, a3};
    #pragma unroll
    for (int k = 0; k < 5; ++k) {
        float v = vals[k];
        #pragma unroll
        for (int off = 32; off > 0; off >>= 1) v += __shfl_down(v, off, 64);
        if (lane == 0) sred[k][wv] = v;
    }
    __syncthreads();
    if (tid < 5) {
        partial[(c * NBLK + bx) * 5 + tid] =
            sred[tid][0] + sred[tid][1] + sred[tid][2] + sred[tid][3];
    }
}

__global__ __launch_bounds__(256) void finalize_kernel(
    const float* __restrict__ det_class,  // [N_OBJ, C_DET]
    const int* __restrict__ edge_i,
    const int* __restrict__ edge_j,
    const int n_edges,
    const float* __restrict__ partial,
    float* __restrict__ out)
{
    const int tid = threadIdx.x;

    // Prefetch det_class into registers to hide the cold miss behind stage 1.
    f32x4 ra[4], rb[4];
    #pragma unroll
    for (int r = 0; r < 4; ++r) {
        const int n = tid + 256 * r;
        ra[r] = *reinterpret_cast<const f32x4*>(det_class + n * C_DET);
        rb[r] = *reinterpret_cast<const f32x4*>(det_class + n * C_DET + 4);
    }

    // Stage 1: reduce 7840 partials -> DA[c*5+k] (k=0 denom, 1..4 A[c][s]).
    __shared__ float DA[C_DET * 5];
    if (tid < C_DET * 5) DA[tid] = 0.f;
    __syncthreads();
    for (int f = tid; f < NPART; f += 256) {
        const int cb = f / 5;
        const int k  = f - cb * 5;
        const int cc = cb / NBLK;
        atomicAdd(&DA[cc * 5 + k], partial[f]);
    }
    __syncthreads();

    // Stage 2: per-edge weights accumulated onto det class j.
    __shared__ float wsh[C_DET];
    if (tid < C_DET) wsh[tid] = 0.f;
    __syncthreads();
    if (tid < n_edges) {
        const int i = edge_i[tid];
        const int j = edge_j[tid];
        atomicAdd(&wsh[j], DA[j * 5 + 1 + i] / DA[j * 5]);
    }
    __syncthreads();

    float wl[C_DET];
    #pragma unroll
    for (int k = 0; k < C_DET; ++k) wl[k] = wsh[k];

    // Stage 3: probs = det_class @ w; loss = mean(-clip(log p, -100)).
    float acc = 0.f;
    #pragma unroll
    for (int r = 0; r < 4; ++r) {
        const float p = ra[r].x * wl[0] + ra[r].y * wl[1]
                      + ra[r].z * wl[2] + ra[r].w * wl[3]
                      + rb[r].x * wl[4] + rb[r].y * wl[5]
                      + rb[r].z * wl[6] + rb[r].w * wl[7];
        acc += -fmaxf(logf(p), -100.f);
    }

    __shared__ float fred[4];
    const int lane = tid & 63;
    const int wv   = tid >> 6;
    float v = acc;
    #pragma unroll
    for (int off = 32; off > 0; off >>= 1) v += __shfl_down(v, off, 64);
    if (lane == 0) fred[wv] = v;
    __syncthreads();
    if (tid == 0)
        out[0] = (fred[0] + fred[1] + fred[2] + fred[3]) * (1.0f / N_OBJ);
}

extern "C" void kernel_launch(void* const* d_in, const int* in_sizes, int n_in,
                              void* d_out, int out_size, void* d_ws, size_t ws_size,
                              hipStream_t stream) {
    const float* det_class = (const float*)d_in[0];   // [1024, 8]
    const float* det       = (const float*)d_in[1];   // [1024, 8, 28, 28]
    const float* seg       = (const float*)d_in[2];   // [1024, 8, 4, 28, 28]
    const int*   edge_i    = (const int*)d_in[3];
    const int*   edge_j    = (const int*)d_in[4];
    const int    n_edges   = in_sizes[3];
    float* out = (float*)d_out;
    float* partial = (float*)d_ws;   // 7840 floats

    overlap_kernel<<<dim3(NBLK, C_DET), 256, 0, stream>>>(det, seg, partial);
    finalize_kernel<<<1, 256, 0, stream>>>(det_class, edge_i, edge_j, n_edges,
                                           partial, out);
}

// Round 5
// 174.712 us; speedup vs baseline: 1.7249x; 1.0357x over previous
//
#include <hip/hip_runtime.h>
#include <math.h>

#define N_OBJ 1024
#define C_DET 8
#define C_SEG 4
#define HW    784      // 28*28
#define HW4   196      // HW/4 (float4 units)
#define NBLK  128      // best-measured grid: (128, 8), 6.125 iters/thread
#define NPART (C_DET * NBLK * 5)   // 5120 partial floats

typedef float f32x4 __attribute__((ext_vector_type(4)));

// d_ws layout: float partial[NPART].
// partial[(c*NBLK+bx)*5 + k]: k=0 denom partial, k=1..4 A[c][k-1] partial.

__global__ __launch_bounds__(256) void overlap_kernel(
    const float* __restrict__ det,   // [N_OBJ, C_DET, HW]
    const float* __restrict__ seg,   // [N_OBJ, C_DET, C_SEG, HW]
    float* __restrict__ partial)
{
    const int c   = blockIdx.y;
    const int bx  = blockIdx.x;
    const int tid = threadIdx.x;

    float accD = 0.f, a0 = 0.f, a1 = 0.f, a2 = 0.f, a3 = 0.f;

    const int total4 = N_OBJ * HW4;  // 200704
    const int step   = NBLK * 256;   // 32768

    auto body = [&](int t4) {
        const int n  = t4 / HW4;                 // magic-mul div
        const int p4 = t4 - n * HW4;
        const int drow = (n * C_DET + c) * HW + p4 * 4;
        const f32x4 d = __builtin_nontemporal_load(
            reinterpret_cast<const f32x4*>(det + drow));
        const int srow = (n * C_DET + c) * (C_SEG * HW) + p4 * 4;
        const f32x4 s0 = __builtin_nontemporal_load(
            reinterpret_cast<const f32x4*>(seg + srow + 0 * HW));
        const f32x4 s1 = __builtin_nontemporal_load(
            reinterpret_cast<const f32x4*>(seg + srow + 1 * HW));
        const f32x4 s2 = __builtin_nontemporal_load(
            reinterpret_cast<const f32x4*>(seg + srow + 2 * HW));
        const f32x4 s3 = __builtin_nontemporal_load(
            reinterpret_cast<const f32x4*>(seg + srow + 3 * HW));
        accD += (d.x + d.y) + (d.z + d.w);
        a0 += s0.x * d.x + s0.y * d.y + s0.z * d.z + s0.w * d.w;
        a1 += s1.x * d.x + s1.y * d.y + s1.z * d.z + s1.w * d.w;
        a2 += s2.x * d.x + s2.y * d.y + s2.z * d.z + s2.w * d.w;
        a3 += s3.x * d.x + s3.y * d.y + s3.z * d.z + s3.w * d.w;
    };

    int t4 = bx * 256 + tid;
    // 2-way unroll: 10 outstanding 16B loads per thread
    for (; t4 + step < total4; t4 += 2 * step) {
        body(t4);
        body(t4 + step);
    }
    if (t4 < total4) body(t4);

    // ---- block-reduce 5 scalars: wave shuffle -> LDS -> partial store ----
    __shared__ float sred[5][4];
    const int lane = tid & 63;
    const int wv   = tid >> 6;
    float vals[5] = {accD, a0, a1, a2, a3};
    #pragma unroll
    for (int k = 0; k < 5; ++k) {
        float v = vals[k];
        #pragma unroll
        for (int off = 32; off > 0; off >>= 1) v += __shfl_down(v, off, 64);
        if (lane == 0) sred[k][wv] = v;
    }
    __syncthreads();
    if (tid < 5) {
        partial[(c * NBLK + bx) * 5 + tid] =
            sred[tid][0] + sred[tid][1] + sred[tid][2] + sred[tid][3];
    }
}

__global__ __launch_bounds__(256) void finalize_kernel(
    const float* __restrict__ det_class,  // [N_OBJ, C_DET]
    const int* __restrict__ edge_i,
    const int* __restrict__ edge_j,
    const int n_edges,
    const float* __restrict__ partial,
    float* __restrict__ out)
{
    const int tid = threadIdx.x;

    // Prefetch det_class into registers to hide the cold miss behind stage 1.
    f32x4 ra[4], rb[4];
    #pragma unroll
    for (int r = 0; r < 4; ++r) {
        const int n = tid + 256 * r;
        ra[r] = *reinterpret_cast<const f32x4*>(det_class + n * C_DET);
        rb[r] = *reinterpret_cast<const f32x4*>(det_class + n * C_DET + 4);
    }

    // Stage 1: reduce 5120 partials -> DA[c*5+k] (k=0 denom, 1..4 A[c][s]).
    __shared__ float DA[C_DET * 5];
    if (tid < C_DET * 5) DA[tid] = 0.f;
    __syncthreads();
    for (int f = tid; f < NPART; f += 256) {
        const int cb = f / 5;
        const int k  = f - cb * 5;
        const int cc = cb / NBLK;
        atomicAdd(&DA[cc * 5 + k], partial[f]);
    }
    __syncthreads();

    // Stage 2: per-edge weights accumulated onto det class j.
    __shared__ float wsh[C_DET];
    if (tid < C_DET) wsh[tid] = 0.f;
    __syncthreads();
    if (tid < n_edges) {
        const int i = edge_i[tid];
        const int j = edge_j[tid];
        atomicAdd(&wsh[j], DA[j * 5 + 1 + i] / DA[j * 5]);
    }
    __syncthreads();

    float wl[C_DET];
    #pragma unroll
    for (int k = 0; k < C_DET; ++k) wl[k] = wsh[k];

    // Stage 3: probs = det_class @ w; loss = mean(-clip(log p, -100)).
    float acc = 0.f;
    #pragma unroll
    for (int r = 0; r < 4; ++r) {
        const float p = ra[r].x * wl[0] + ra[r].y * wl[1]
                      + ra[r].z * wl[2] + ra[r].w * wl[3]
                      + rb[r].x * wl[4] + rb[r].y * wl[5]
                      + rb[r].z * wl[6] + rb[r].w * wl[7];
        acc += -fmaxf(logf(p), -100.f);
    }

    __shared__ float fred[4];
    const int lane = tid & 63;
    const int wv   = tid >> 6;
    float v = acc;
    #pragma unroll
    for (int off = 32; off > 0; off >>= 1) v += __shfl_down(v, off, 64);
    if (lane == 0) fred[wv] = v;
    __syncthreads();
    if (tid == 0)
        out[0] = (fred[0] + fred[1] + fred[2] + fred[3]) * (1.0f / N_OBJ);
}

extern "C" void kernel_launch(void* const* d_in, const int* in_sizes, int n_in,
                              void* d_out, int out_size, void* d_ws, size_t ws_size,
                              hipStream_t stream) {
    const float* det_class = (const float*)d_in[0];   // [1024, 8]
    const float* det       = (const float*)d_in[1];   // [1024, 8, 28, 28]
    const float* seg       = (const float*)d_in[2];   // [1024, 8, 4, 28, 28]
    const int*   edge_i    = (const int*)d_in[3];
    const int*   edge_j    = (const int*)d_in[4];
    const int    n_edges   = in_sizes[3];
    float* out = (float*)d_out;
    float* partial = (float*)d_ws;   // 5120 floats

    overlap_kernel<<<dim3(NBLK, C_DET), 256, 0, stream>>>(det, seg, partial);
    finalize_kernel<<<1, 256, 0, stream>>>(det_class, edge_i, edge_j, n_edges,
                                           partial, out);
}